// Round 3
// baseline (49.344 us; speedup 1.0000x reference)
//
#include <hip/hip_runtime.h>
#include <hip/hip_cooperative_groups.h>
#include <math.h>

namespace cg = cooperative_groups;

#define NPTS   543
#define NPER   (NPTS*3)      // 1629 floats per frame
#define MAXL   256
#define NFEAT  1230

__constant__ int c_LIP[40] = {61, 146, 91, 181, 84, 17, 314, 405, 321, 375,
                              291, 78, 95, 88, 178, 87, 14, 317, 402, 318,
                              324, 308, 191, 80, 81, 82, 13, 312, 311, 310,
                              415, 185, 40, 39, 37, 0, 267, 269, 270, 409};
__constant__ int c_SPOSE[8] = {500, 502, 504, 501, 503, 505, 512, 513};

__device__ __forceinline__ bool not_nan(float f) { return f == f; }

// Single cooperative kernel: grid = L blocks x 256 threads.
//  phase 1: grid-stride NaN-aware partial (sum, sumsq, cnt) -> part[blockIdx]
//  phase 2: gather raw 90-point sets for frames t-1/t/t+1 into LDS (no
//           cross-block dep -> overlaps the grid barrier wait)
//  phase 3: grid.sync()
//  phase 4: every block reduces the gridDim partials -> (m, 1/s)
//  phase 5: emit the 1230 features for frame t
__global__ void __launch_bounds__(256)
fused(const float* __restrict__ xyz, float* __restrict__ out,
      double* __restrict__ part, int n, int i0, int L) {
    __shared__ double s_sum[256], s_sq[256], s_cnt[256];
    __shared__ float p_cur[270], p_prev[270], p_next[270];
    __shared__ float s_m, s_is;

    const int t   = blockIdx.x;
    const int tid = threadIdx.x;
    const bool has_prev = (t > 0);
    const bool has_next = (t < L - 1);

    // ---- phase 1: partial reduction over all input elements ----
    {
        const long long gtid   = (long long)t * blockDim.x + tid;
        const long long stride = (long long)gridDim.x * blockDim.x;
        double sum = 0.0, sq = 0.0, cnt = 0.0;
        const int n4 = n >> 2;
        const float4* x4 = (const float4*)xyz;
        for (long long i = gtid; i < n4; i += stride) {
            float4 v = x4[i];
            float a[4] = {v.x, v.y, v.z, v.w};
            #pragma unroll
            for (int k = 0; k < 4; ++k) {
                float f = a[k];
                if (not_nan(f)) { sum += f; sq += (double)f * f; cnt += 1.0; }
            }
        }
        const int tail0 = n4 << 2;
        if (gtid < (n - tail0)) {
            float f = xyz[tail0 + gtid];
            if (not_nan(f)) { sum += f; sq += (double)f * f; cnt += 1.0; }
        }
        s_sum[tid] = sum; s_sq[tid] = sq; s_cnt[tid] = cnt;
        __syncthreads();
        for (int off = 128; off > 0; off >>= 1) {
            if (tid < off) {
                s_sum[tid] += s_sum[tid + off];
                s_sq[tid]  += s_sq[tid + off];
                s_cnt[tid] += s_cnt[tid + off];
            }
            __syncthreads();
        }
        if (tid == 0) {
            // agent-scope stores: per-XCD L2s are not cross-coherent
            __hip_atomic_store(&part[t * 3 + 0], s_sum[0], __ATOMIC_RELAXED, __HIP_MEMORY_SCOPE_AGENT);
            __hip_atomic_store(&part[t * 3 + 1], s_sq[0],  __ATOMIC_RELAXED, __HIP_MEMORY_SCOPE_AGENT);
            __hip_atomic_store(&part[t * 3 + 2], s_cnt[0], __ATOMIC_RELAXED, __HIP_MEMORY_SCOPE_AGENT);
        }
    }

    // ---- phase 2: gather raw points (independent of stats) ----
    for (int idx = tid; idx < 810; idx += 256) {
        const int f = idx / 270;            // 0=cur 1=prev 2=next
        const int e = idx - f * 270;
        const int p = e / 3, c = e - p * 3;
        const int lm = (p < 21) ? (468 + p)
                     : (p < 42) ? (501 + p)
                     : (p < 82) ? c_LIP[p - 42]
                                : c_SPOSE[p - 82];
        const long long off = (long long)lm * 3 + c;
        if (f == 0) {
            p_cur[e] = xyz[(long long)(i0 + t) * NPER + off];
        } else if (f == 1) {
            p_prev[e] = has_prev ? xyz[(long long)(i0 + t - 1) * NPER + off] : 0.0f;
        } else {
            p_next[e] = has_next ? xyz[(long long)(i0 + t + 1) * NPER + off] : 0.0f;
        }
    }

    // ---- phase 3: grid-wide barrier ----
    cg::this_grid().sync();

    // ---- phase 4: every block reduces the gridDim partial triples ----
    {
        const int nb = gridDim.x;
        double sum = 0.0, sq = 0.0, cnt = 0.0;
        if (tid < nb) {
            sum = __hip_atomic_load(&part[tid * 3 + 0], __ATOMIC_RELAXED, __HIP_MEMORY_SCOPE_AGENT);
            sq  = __hip_atomic_load(&part[tid * 3 + 1], __ATOMIC_RELAXED, __HIP_MEMORY_SCOPE_AGENT);
            cnt = __hip_atomic_load(&part[tid * 3 + 2], __ATOMIC_RELAXED, __HIP_MEMORY_SCOPE_AGENT);
        }
        s_sum[tid] = sum; s_sq[tid] = sq; s_cnt[tid] = cnt;
        __syncthreads();
        for (int off = 128; off > 0; off >>= 1) {
            if (tid < off) {
                s_sum[tid] += s_sum[tid + off];
                s_sq[tid]  += s_sq[tid + off];
                s_cnt[tid] += s_cnt[tid + off];
            }
            __syncthreads();
        }
        if (tid == 0) {
            double m   = s_sum[0] / s_cnt[0];
            double var = (s_sq[0] - s_sum[0] * s_sum[0] / s_cnt[0]) / (s_cnt[0] - 1.0);
            s_m  = (float)m;
            s_is = (float)(1.0 / sqrt(var));
        }
        __syncthreads();
    }

    // ---- phase 5: emit features ----
    const float m     = s_m;
    const float inv_s = s_is;
    float* orow = out + (long long)t * NFEAT;
    for (int col = tid; col < NFEAT; col += 256) {
        float v;
        if (col < 270) {
            v = (p_cur[col] - m) * inv_s;
        } else if (col < 540) {               // dfxyz[t] = pts[t] - pts[t+1], 0 at t=L-1
            const int idx = col - 270;
            v = has_next ? (p_cur[idx] - p_next[idx]) * inv_s : 0.0f;
        } else if (col < 810) {               // dbxyz[t] = pts[t] - pts[t-1], 0 at t=0
            const int idx = col - 540;
            v = has_prev ? (p_cur[idx] - p_prev[idx]) * inv_s : 0.0f;
        } else {                              // ld (210) then rd (210)
            int k = col - 810;
            int base = 0;
            if (k >= 210) { k -= 210; base = 21; }
            int i = 0, rem = k, row = 20;     // strict upper-triangle of 21
            while (rem >= row) { rem -= row; --row; ++i; }
            const int j = i + 1 + rem;
            const float dx = p_cur[(base + i) * 3 + 0] - p_cur[(base + j) * 3 + 0];
            const float dy = p_cur[(base + i) * 3 + 1] - p_cur[(base + j) * 3 + 1];
            v = sqrtf(dx * dx + dy * dy) * inv_s;
        }
        orow[col] = not_nan(v) ? v : 0.0f;    // final NaN -> 0
    }
}

extern "C" void kernel_launch(void* const* d_in, const int* in_sizes, int n_in,
                              void* d_out, int out_size, void* d_ws, size_t ws_size,
                              hipStream_t stream) {
    const float* xyz = (const float*)d_in[0];
    float* out = (float*)d_out;
    int n    = in_sizes[0];
    const int L_in = n / NPER;
    int i0 = (L_in > MAXL) ? (L_in - MAXL) / 2 : 0;
    int L  = (L_in > MAXL) ? MAXL : L_in;

    double* part = (double*)d_ws;

    void* args[] = {(void*)&xyz, (void*)&out, (void*)&part,
                    (void*)&n, (void*)&i0, (void*)&L};
    hipLaunchCooperativeKernel((void*)fused, dim3(L), dim3(256), args, 0, stream);
}

// Round 4
// 15.701 us; speedup vs baseline: 3.1426x; 3.1426x over previous
//
#include <hip/hip_runtime.h>
#include <math.h>

#define NPTS   543
#define NPER   (NPTS*3)      // 1629 floats per frame
#define MAXL   256
#define NFEAT  1230
#define NB1    256           // kernel1 blocks == partial count
#define ROWP   272           // compacted row stride (270 pts padded to 16B)

__constant__ int c_LIP[40] = {61, 146, 91, 181, 84, 17, 314, 405, 321, 375,
                              291, 78, 95, 88, 178, 87, 14, 317, 402, 318,
                              324, 308, 191, 80, 81, 82, 13, 312, 311, 310,
                              415, 185, 40, 39, 37, 0, 267, 269, 270, 409};
__constant__ int c_SPOSE[8] = {500, 502, 504, 501, 503, 505, 512, 513};

__device__ __forceinline__ bool not_nan(float f) { return f == f; }

// Kernel 1: (a) grid-stride NaN-aware partial (sum,sumsq,cnt) -> part[block]
//           (b) compact the 90 gather-points of frame t=blockIdx into
//               pts[t*ROWP .. +270) (scattered reads hide under (a)'s latency)
__global__ void __launch_bounds__(256)
k1(const float* __restrict__ xyz, int n, int i0, int L,
   double* __restrict__ part, float* __restrict__ pts) {
    __shared__ double s_sum[256], s_sq[256], s_cnt[256];
    const int t   = blockIdx.x;
    const int tid = threadIdx.x;

    // (b) issue the scattered gather first so it overlaps the reduce
    if (t < L) {
        for (int e = tid; e < 270; e += 256) {
            const int p = e / 3, c = e - p * 3;
            const int lm = (p < 21) ? (468 + p)
                         : (p < 42) ? (501 + p)
                         : (p < 82) ? c_LIP[p - 42]
                                    : c_SPOSE[p - 82];
            pts[t * ROWP + e] = xyz[(long long)(i0 + t) * NPER + lm * 3 + c];
        }
    }

    // (a) partial reduction
    {
        const long long gtid   = (long long)t * 256 + tid;
        const long long stride = (long long)gridDim.x * 256;
        double sum = 0.0, sq = 0.0, cnt = 0.0;
        const int n4 = n >> 2;
        const float4* x4 = (const float4*)xyz;
        for (long long i = gtid; i < n4; i += stride) {
            float4 v = x4[i];
            float a[4] = {v.x, v.y, v.z, v.w};
            #pragma unroll
            for (int k = 0; k < 4; ++k) {
                float f = a[k];
                if (not_nan(f)) { sum += f; sq += (double)f * f; cnt += 1.0; }
            }
        }
        const int tail0 = n4 << 2;
        if (gtid < (n - tail0)) {
            float f = xyz[tail0 + gtid];
            if (not_nan(f)) { sum += f; sq += (double)f * f; cnt += 1.0; }
        }
        s_sum[tid] = sum; s_sq[tid] = sq; s_cnt[tid] = cnt;
        __syncthreads();
        for (int off = 128; off > 0; off >>= 1) {
            if (tid < off) {
                s_sum[tid] += s_sum[tid + off];
                s_sq[tid]  += s_sq[tid + off];
                s_cnt[tid] += s_cnt[tid + off];
            }
            __syncthreads();
        }
        if (tid == 0) {
            part[t * 3 + 0] = s_sum[0];
            part[t * 3 + 1] = s_sq[0];
            part[t * 3 + 2] = s_cnt[0];
        }
    }
}

// Kernel 2: wave 0 reduces the 256 partial triples -> (m, 1/s) while waves
// 1-3 stage the compacted prev/cur/next rows; then emit the 1230 features.
__global__ void __launch_bounds__(256)
k2(const float* __restrict__ pts, const double* __restrict__ part,
   float* __restrict__ out, int L) {
    __shared__ float p_cur[272], p_prev[272], p_next[272];
    __shared__ float s_m, s_is;
    const int t   = blockIdx.x;
    const int tid = threadIdx.x;
    const bool has_prev = (t > 0);
    const bool has_next = (t < L - 1);

    if (tid < 64) {
        // one wave: 4 triples/lane + butterfly
        double sum = 0.0, sq = 0.0, cnt = 0.0;
        #pragma unroll
        for (int q = 0; q < 4; ++q) {
            const int b = tid * 4 + q;
            sum += part[b * 3 + 0];
            sq  += part[b * 3 + 1];
            cnt += part[b * 3 + 2];
        }
        #pragma unroll
        for (int off = 32; off > 0; off >>= 1) {
            sum += __shfl_down(sum, off, 64);
            sq  += __shfl_down(sq,  off, 64);
            cnt += __shfl_down(cnt, off, 64);
        }
        if (tid == 0) {
            double m   = sum / cnt;
            double var = (sq - sum * sum / cnt) / (cnt - 1.0);
            s_m  = (float)m;
            s_is = (float)(1.0 / sqrt(var));
        }
    } else {
        // waves 1-3: stage 3 contiguous rows as float4 (ROWP=272 -> 68 vec4/row)
        const int w = tid - 64;                     // 0..191
        float4* dc = (float4*)p_cur;
        float4* dp = (float4*)p_prev;
        float4* dn = (float4*)p_next;
        const float4* sc = (const float4*)(pts + (long long)t * ROWP);
        const float4* sp = (const float4*)(pts + (long long)(t - 1) * ROWP);
        const float4* sn = (const float4*)(pts + (long long)(t + 1) * ROWP);
        const float4 z = {0.f, 0.f, 0.f, 0.f};
        for (int idx = w; idx < 204; idx += 192) {
            const int f = idx / 68;                 // 0=cur 1=prev 2=next
            const int e = idx - f * 68;
            if (f == 0)      dc[e] = sc[e];
            else if (f == 1) dp[e] = has_prev ? sp[e] : z;
            else             dn[e] = has_next ? sn[e] : z;
        }
    }
    __syncthreads();

    const float m     = s_m;
    const float inv_s = s_is;
    float* orow = out + (long long)t * NFEAT;
    for (int col = tid; col < NFEAT; col += 256) {
        float v;
        if (col < 270) {
            v = (p_cur[col] - m) * inv_s;
        } else if (col < 540) {               // dfxyz[t] = pts[t] - pts[t+1], 0 at t=L-1
            const int idx = col - 270;
            v = has_next ? (p_cur[idx] - p_next[idx]) * inv_s : 0.0f;
        } else if (col < 810) {               // dbxyz[t] = pts[t] - pts[t-1], 0 at t=0
            const int idx = col - 540;
            v = has_prev ? (p_cur[idx] - p_prev[idx]) * inv_s : 0.0f;
        } else {                              // ld (210) then rd (210)
            int k = col - 810;
            int base = 0;
            if (k >= 210) { k -= 210; base = 21; }
            int i = 0, rem = k, row = 20;     // strict upper-triangle of 21
            while (rem >= row) { rem -= row; --row; ++i; }
            const int j = i + 1 + rem;
            const float dx = p_cur[(base + i) * 3 + 0] - p_cur[(base + j) * 3 + 0];
            const float dy = p_cur[(base + i) * 3 + 1] - p_cur[(base + j) * 3 + 1];
            v = sqrtf(dx * dx + dy * dy) * inv_s;
        }
        orow[col] = not_nan(v) ? v : 0.0f;    // final NaN -> 0
    }
}

extern "C" void kernel_launch(void* const* d_in, const int* in_sizes, int n_in,
                              void* d_out, int out_size, void* d_ws, size_t ws_size,
                              hipStream_t stream) {
    const float* xyz = (const float*)d_in[0];
    float* out = (float*)d_out;
    const int n    = in_sizes[0];
    const int L_in = n / NPER;
    const int i0   = (L_in > MAXL) ? (L_in - MAXL) / 2 : 0;
    const int L    = (L_in > MAXL) ? MAXL : L_in;

    double* part = (double*)d_ws;                            // NB1*3 doubles
    float*  pts  = (float*)((char*)d_ws + NB1 * 3 * sizeof(double)); // [MAXL][ROWP]

    k1<<<NB1, 256, 0, stream>>>(xyz, n, i0, L, part, pts);
    k2<<<L,   256, 0, stream>>>(pts, part, out, L);
}